// Round 4
// baseline (1542.268 us; speedup 1.0000x reference)
//
#include <hip/hip_runtime.h>

#define N_DIM 256
#define BATCH 64
#define CPT 4   // columns per thread
#define BS 64   // one wave per block

// Full-wave (64-lane) f32 min via DPP: row_shr 1/2/4/8 then row_bcast15/31.
#define DPP_MIN_STEP(x, ctrl) do {                                            \
    int _s = __builtin_amdgcn_update_dpp(__float_as_int(x), __float_as_int(x),\
                                         (ctrl), 0xf, 0xf, false);            \
    (x) = fminf((x), __int_as_float(_s));                                     \
} while (0)

__device__ __forceinline__ float wave_min_f32(float x) {
    DPP_MIN_STEP(x, 0x111);  // row_shr:1
    DPP_MIN_STEP(x, 0x112);  // row_shr:2
    DPP_MIN_STEP(x, 0x114);  // row_shr:4
    DPP_MIN_STEP(x, 0x118);  // row_shr:8
    DPP_MIN_STEP(x, 0x142);  // row_bcast15
    DPP_MIN_STEP(x, 0x143);  // row_bcast31
    return __int_as_float(__builtin_amdgcn_readlane(__float_as_int(x), 63));
}

// uniform (gmin, gcol) argmin over the wave from per-lane (cv, cc)
#define WAVE_ARGMIN(cv, cc, gmin, gcol) do {                                  \
    (gmin) = wave_min_f32(cv);                                                \
    const unsigned long long _m = __ballot((cv) == (gmin));                   \
    const int _wl = __ffsll((long long)_m) - 1;                               \
    (gcol) = __builtin_amdgcn_readlane((cc), _wl);                            \
} while (0)

// row4col lookup from the per-lane register mirror (col uniform)
#define MIRROR(col, out) do {                                                 \
    const int _src = (col) >> 2, _sel = (col) & 3;                            \
    const int _r0 = __builtin_amdgcn_readlane(r4c0, _src);                    \
    const int _r1 = __builtin_amdgcn_readlane(r4c1, _src);                    \
    const int _r2 = __builtin_amdgcn_readlane(r4c2, _src);                    \
    const int _r3 = __builtin_amdgcn_readlane(r4c3, _src);                    \
    const int _a = (_sel & 1) ? _r1 : _r0;                                    \
    const int _b = (_sel & 1) ? _r3 : _r2;                                    \
    (out) = (_sel & 2) ? _b : _a;                                             \
} while (0)

// One block = one wave = one batch element. Lane t owns columns/rows 4t..4t+3.
// JV LAP: column reduction -> greedy -> augmenting row reduction (2 passes) ->
// shortest augmenting path for leftovers. Duals stay feasible + matched-tight
// throughout, so the final matching is exactly optimal regardless of how many
// rows ARR resolves.
__global__ __launch_bounds__(BS) void lap_kernel(const float* __restrict__ Dm,
                                                 double* __restrict__ batch_sums) {
    const int b = blockIdx.x;
    const int t = threadIdx.x;  // 0..63
    const float* __restrict__ cost = Dm + (size_t)b * N_DIM * N_DIM;
    const float4* __restrict__ cost4 = (const float4*)cost;

    __shared__ float u_s[N_DIM];
    __shared__ int   row4col_s[N_DIM];
    __shared__ int   col4row_s[N_DIM];
    __shared__ int   path_s[N_DIM];
    __shared__ int   rowcand_s[N_DIM];

    float v0, v1, v2, v3;          // column duals (lane t: cols 4t..4t+3)
    float spc0, spc1, spc2, spc3;  // shortest-path costs
    int   r4c0, r4c1, r4c2, r4c3;  // row4col register mirror

    // ---- column reduction: v[j] = min_i cost[i][j] + candidate row ----
    float cmn0 = INFINITY, cmn1 = INFINITY, cmn2 = INFINITY, cmn3 = INFINITY;
    int   ca0 = 0, ca1 = 0, ca2 = 0, ca3 = 0;
    for (int r = 0; r < N_DIM; ++r) {
        const float4 c4 = cost4[r * BS + t];
        if (c4.x < cmn0) { cmn0 = c4.x; ca0 = r; }
        if (c4.y < cmn1) { cmn1 = c4.y; ca1 = r; }
        if (c4.z < cmn2) { cmn2 = c4.z; ca2 = r; }
        if (c4.w < cmn3) { cmn3 = c4.w; ca3 = r; }
    }
    v0 = cmn0; v1 = cmn1; v2 = cmn2; v3 = cmn3;
    {
        const int c = t * CPT;
        u_s[c] = 0.0f; u_s[c + 1] = 0.0f; u_s[c + 2] = 0.0f; u_s[c + 3] = 0.0f;
        row4col_s[c] = -1; row4col_s[c + 1] = -1; row4col_s[c + 2] = -1; row4col_s[c + 3] = -1;
        col4row_s[c] = -1; col4row_s[c + 1] = -1; col4row_s[c + 2] = -1; col4row_s[c + 3] = -1;
        rowcand_s[c] = 0x7fffffff; rowcand_s[c + 1] = 0x7fffffff;
        rowcand_s[c + 2] = 0x7fffffff; rowcand_s[c + 3] = 0x7fffffff;
    }
    __syncthreads();
    // greedy: each candidate row goes to the lowest claiming column
    atomicMin(&rowcand_s[ca0], t * CPT + 0);
    atomicMin(&rowcand_s[ca1], t * CPT + 1);
    atomicMin(&rowcand_s[ca2], t * CPT + 2);
    atomicMin(&rowcand_s[ca3], t * CPT + 3);
    __syncthreads();
    if (rowcand_s[ca0] == t * CPT + 0) { row4col_s[t * CPT + 0] = ca0; col4row_s[ca0] = t * CPT + 0; }
    if (rowcand_s[ca1] == t * CPT + 1) { row4col_s[t * CPT + 1] = ca1; col4row_s[ca1] = t * CPT + 1; }
    if (rowcand_s[ca2] == t * CPT + 2) { row4col_s[t * CPT + 2] = ca2; col4row_s[ca2] = t * CPT + 2; }
    if (rowcand_s[ca3] == t * CPT + 3) { row4col_s[t * CPT + 3] = ca3; col4row_s[ca3] = t * CPT + 3; }
    __syncthreads();

    // mirror init + free-row masks (mask K, bit T <-> row 4T+K)
    {
        const int4 m4 = ((const int4*)row4col_s)[t];
        r4c0 = m4.x; r4c1 = m4.y; r4c2 = m4.z; r4c3 = m4.w;
    }
    const int4 y4 = ((const int4*)col4row_s)[t];
    unsigned long long cm0 = __ballot(y4.x < 0);
    unsigned long long cm1 = __ballot(y4.y < 0);
    unsigned long long cm2 = __ballot(y4.z < 0);
    unsigned long long cm3 = __ballot(y4.w < 0);

    // ---- augmenting row reduction (2 passes, guarded) ----
    for (int pass = 0; pass < 2; ++pass) {
        unsigned long long nm0 = 0, nm1 = 0, nm2 = 0, nm3 = 0;
        int inext = -1;
        int guard = 0;
        while (guard < 640) {
            int i;
            if (inext >= 0) { i = inext; inext = -1; }
            else if (cm0) { const int tt = __builtin_ctzll(cm0); cm0 &= cm0 - 1; i = tt * 4 + 0; }
            else if (cm1) { const int tt = __builtin_ctzll(cm1); cm1 &= cm1 - 1; i = tt * 4 + 1; }
            else if (cm2) { const int tt = __builtin_ctzll(cm2); cm2 &= cm2 - 1; i = tt * 4 + 2; }
            else if (cm3) { const int tt = __builtin_ctzll(cm3); cm3 &= cm3 - 1; i = tt * 4 + 3; }
            else break;
            ++guard;

            const float4 c4 = cost4[i * BS + t];
            const float rc0 = c4.x - v0, rc1 = c4.y - v1;
            const float rc2 = c4.z - v2, rc3 = c4.w - v3;

            // argmin1
            float cv = rc0; int cc = t * CPT + 0;
            if (rc1 < cv) { cv = rc1; cc = t * CPT + 1; }
            if (rc2 < cv) { cv = rc2; cc = t * CPT + 2; }
            if (rc3 < cv) { cv = rc3; cc = t * CPT + 3; }
            float u1; int j1;
            WAVE_ARGMIN(cv, cc, u1, j1);

            // argmin2 (exclude j1)
            float cv2 = INFINITY; int cc2 = 0;
            if (t * CPT + 0 != j1 && rc0 < cv2) { cv2 = rc0; cc2 = t * CPT + 0; }
            if (t * CPT + 1 != j1 && rc1 < cv2) { cv2 = rc1; cc2 = t * CPT + 1; }
            if (t * CPT + 2 != j1 && rc2 < cv2) { cv2 = rc2; cc2 = t * CPT + 2; }
            if (t * CPT + 3 != j1 && rc3 < cv2) { cv2 = rc3; cc2 = t * CPT + 3; }
            float u2; int j2;
            WAVE_ARGMIN(cv2, cc2, u2, j2);

            const bool strict = (u1 < u2);
            int jt = j1;
            if (!strict) {
                int occ; MIRROR(j1, occ);
                if (occ >= 0) jt = j2;
            }
            int i0; MIRROR(jt, i0);

            if (strict && t == (j1 >> 2)) {
                const float d = u2 - u1;
                const int s = j1 & 3;
                if (s == 0) v0 -= d; else if (s == 1) v1 -= d;
                else if (s == 2) v2 -= d; else v3 -= d;
            }
            if (t == 0) {
                u_s[i] = u2;
                col4row_s[i] = jt;
                row4col_s[jt] = i;
                if (i0 >= 0) col4row_s[i0] = -1;
            }
            if (t == (jt >> 2)) {
                const int s = jt & 3;
                if (s == 0) r4c0 = i; else if (s == 1) r4c1 = i;
                else if (s == 2) r4c2 = i; else r4c3 = i;
            }
            if (i0 >= 0) {
                if (strict) { inext = i0; }
                else {
                    const int kk = i0 & 3, tt = i0 >> 2;
                    if (kk == 0) nm0 |= 1ull << tt; else if (kk == 1) nm1 |= 1ull << tt;
                    else if (kk == 2) nm2 |= 1ull << tt; else nm3 |= 1ull << tt;
                }
            }
        }
        cm0 = nm0; cm1 = nm1; cm2 = nm2; cm3 = nm3;
    }
    __syncthreads();
    {   // mirror refresh (LDS authoritative)
        const int4 m4 = ((const int4*)row4col_s)[t];
        r4c0 = m4.x; r4c1 = m4.y; r4c2 = m4.z; r4c3 = m4.w;
    }

    // ---- shortest augmenting path for remaining free rows ----
    for (int i = 0; i < N_DIM; ++i) {
        if (col4row_s[i] >= 0) continue;  // uniform

        spc0 = INFINITY; spc1 = INFINITY; spc2 = INFINITY; spc3 = INFINITY;
        int   scanmask = 0;
        int   cur = i;
        float minVal = 0.0f;
        int   sink = -1;

        while (true) {
            const float4 c4 = cost4[cur * BS + t];
            const float add = minVal - u_s[cur];  // overlaps the global load

            float cv = INFINITY; int cc = 0;
            if (!(scanmask & 1)) {
                const float r = add + c4.x - v0;
                if (r < spc0) { spc0 = r; path_s[t * CPT + 0] = cur; }
                cv = spc0; cc = t * CPT + 0;
            }
            if (!(scanmask & 2)) {
                const float r = add + c4.y - v1;
                if (r < spc1) { spc1 = r; path_s[t * CPT + 1] = cur; }
                if (spc1 < cv) { cv = spc1; cc = t * CPT + 1; }
            }
            if (!(scanmask & 4)) {
                const float r = add + c4.z - v2;
                if (r < spc2) { spc2 = r; path_s[t * CPT + 2] = cur; }
                if (spc2 < cv) { cv = spc2; cc = t * CPT + 2; }
            }
            if (!(scanmask & 8)) {
                const float r = add + c4.w - v3;
                if (r < spc3) { spc3 = r; path_s[t * CPT + 3] = cur; }
                if (spc3 < cv) { cv = spc3; cc = t * CPT + 3; }
            }

            float gmin; int bi;
            WAVE_ARGMIN(cv, cc, gmin, bi);
            minVal = gmin;
            if ((bi >> 2) == t) scanmask |= 1 << (bi & 3);
            int r4; MIRROR(bi, r4);
            if (r4 < 0) { sink = bi; break; }
            cur = r4;
        }

        // dual update (mirror registers; matched rows of scanned cols distinct)
        if (scanmask & 1) { const float dv = minVal - spc0; v0 -= dv; if (r4c0 >= 0) u_s[r4c0] += dv; }
        if (scanmask & 2) { const float dv = minVal - spc1; v1 -= dv; if (r4c1 >= 0) u_s[r4c1] += dv; }
        if (scanmask & 4) { const float dv = minVal - spc2; v2 -= dv; if (r4c2 >= 0) u_s[r4c2] += dv; }
        if (scanmask & 8) { const float dv = minVal - spc3; v3 -= dv; if (r4c3 >= 0) u_s[r4c3] += dv; }
        if (t == 0) u_s[i] += minVal;

        // augment alternating path (serial, short)
        if (t == 0) {
            int jj = sink;
            while (true) {
                const int ii = path_s[jj];
                row4col_s[jj] = ii;
                const int tmp = col4row_s[ii];
                col4row_s[ii] = jj;
                jj = tmp;
                if (ii == i) break;
            }
        }
        __syncthreads();
        const int4 m4 = ((const int4*)row4col_s)[t];  // refresh mirror
        r4c0 = m4.x; r4c1 = m4.y; r4c2 = m4.z; r4c3 = m4.w;
    }

    // gather matched costs (4 rows per thread) and wave-reduce in f64
    double s = 0.0;
    {
        const int4 y = ((const int4*)col4row_s)[t];
        s += (double)cost[(size_t)(t * CPT + 0) * N_DIM + y.x];
        s += (double)cost[(size_t)(t * CPT + 1) * N_DIM + y.y];
        s += (double)cost[(size_t)(t * CPT + 2) * N_DIM + y.z];
        s += (double)cost[(size_t)(t * CPT + 3) * N_DIM + y.w];
    }
    #pragma unroll
    for (int off = 32; off > 0; off >>= 1) s += __shfl_down(s, off);
    if (t == 0) batch_sums[b] = s;
}

__global__ void finalize_kernel(const double* __restrict__ batch_sums,
                                float* __restrict__ out) {
    const int t = threadIdx.x;  // 64 threads, one wave
    double s = batch_sums[t];
    #pragma unroll
    for (int off = 32; off > 0; off >>= 1) s += __shfl_down(s, off);
    if (t == 0) out[0] = (float)(s / (double)((long long)BATCH * N_DIM));
}

extern "C" void kernel_launch(void* const* d_in, const int* in_sizes, int n_in,
                              void* d_out, int out_size, void* d_ws, size_t ws_size,
                              hipStream_t stream) {
    const float* Dm = (const float*)d_in[0];
    float* out = (float*)d_out;
    double* sums = (double*)d_ws;  // 64 * 8 = 512 bytes

    lap_kernel<<<BATCH, BS, 0, stream>>>(Dm, sums);
    finalize_kernel<<<1, 64, 0, stream>>>(sums, out);
}

// Round 5
// 1271.606 us; speedup vs baseline: 1.2129x; 1.2129x over previous
//
#include <hip/hip_runtime.h>
#include <hip/hip_fp16.h>

#define N_DIM 256
#define BATCH 64
#define BS 64   // one wave per block; lane t owns columns/rows 4t..4t+3

struct __align__(8) H4 { __half2 a, b; };

// monotone f32 -> u32 map (unsigned compare == float ascending)
__device__ __forceinline__ unsigned fmap(float f) {
    unsigned b = __float_as_uint(f);
    return (b & 0x80000000u) ? ~b : (b | 0x80000000u);
}

#define DPP_MINU(x, ctrl) do {                                                 \
    unsigned _s = (unsigned)__builtin_amdgcn_update_dpp((int)(x), (int)(x),    \
                                                        (ctrl), 0xf, 0xf, false); \
    (x) = ((x) < _s) ? (x) : _s;                                               \
} while (0)

// full-wave u32 min via DPP (row_shr 1/2/4/8, row_bcast15/31), bcast from lane 63
__device__ __forceinline__ unsigned wave_min_u32(unsigned x) {
    DPP_MINU(x, 0x111); DPP_MINU(x, 0x112); DPP_MINU(x, 0x114); DPP_MINU(x, 0x118);
    DPP_MINU(x, 0x142); DPP_MINU(x, 0x143);
    return (unsigned)__builtin_amdgcn_readlane((int)x, 63);
}

// uniform-index lookup from 4 per-lane mirror regs: 2 selects + 1 readlane
__device__ __forceinline__ int rd4_i(int x0, int x1, int x2, int x3, int idx) {
    const int sel = idx & 3, src = idx >> 2;
    int ab = (sel & 1) ? x1 : x0;
    int cd = (sel & 1) ? x3 : x2;
    int vv = (sel & 2) ? cd : ab;
    return __builtin_amdgcn_readlane(vv, src);
}
__device__ __forceinline__ float rd4_f(float x0, float x1, float x2, float x3, int idx) {
    return __int_as_float(rd4_i(__float_as_int(x0), __float_as_int(x1),
                                __float_as_int(x2), __float_as_int(x3), idx));
}

// owner-lane mirror update (idx wave-uniform)
#define SET4(x0, x1, x2, x3, idx, val) do {                                    \
    const int _sel = (idx) & 3;                                                \
    if (t == ((idx) >> 2)) {                                                   \
        if (_sel == 0) x0 = (val); else if (_sel == 1) x1 = (val);             \
        else if (_sel == 2) x2 = (val); else x3 = (val);                       \
    }                                                                          \
} while (0)

// One block = one wave = one batch element.
// JV LAP on the fp16-rounded cost matrix (staged in LDS): column reduction +
// greedy init, then shortest augmenting path per free row. All matching state
// (row4col, col4row, path) lives in register mirrors; only u[] and the fp16
// matrix are in LDS. No barriers in the main loop (single wave, DS in-order).
// Final gather evaluates the ORIGINAL f32 costs.
__global__ __launch_bounds__(BS) void lap_kernel(const float* __restrict__ Dm,
                                                 double* __restrict__ batch_sums) {
    const int b = blockIdx.x;
    const int t = threadIdx.x;  // 0..63
    const float* __restrict__ cost = Dm + (size_t)b * N_DIM * N_DIM;
    const float4* __restrict__ cost4 = (const float4*)cost;

    __shared__ float u_s[N_DIM];
    __shared__ int   rowcand_s[N_DIM];
    __shared__ H4    ch[N_DIM * BS];   // [row][lane]: 4 fp16 costs, 128 KB

    const int c0i = t * 4 + 0, c1i = t * 4 + 1, c2i = t * 4 + 2, c3i = t * 4 + 3;

    // ---- stage fp16 matrix + column reduction on ROUNDED values ----
    float cmn0 = INFINITY, cmn1 = INFINITY, cmn2 = INFINITY, cmn3 = INFINITY;
    int   ca0 = 0, ca1 = 0, ca2 = 0, ca3 = 0;
    for (int r = 0; r < N_DIM; ++r) {
        const float4 c4 = cost4[r * BS + t];
        H4 h;
        h.a = __floats2half2_rn(c4.x, c4.y);
        h.b = __floats2half2_rn(c4.z, c4.w);
        ch[r * BS + t] = h;
        const float r0 = __low2float(h.a), r1 = __high2float(h.a);
        const float r2 = __low2float(h.b), r3 = __high2float(h.b);
        if (r0 < cmn0) { cmn0 = r0; ca0 = r; }
        if (r1 < cmn1) { cmn1 = r1; ca1 = r; }
        if (r2 < cmn2) { cmn2 = r2; ca2 = r; }
        if (r3 < cmn3) { cmn3 = r3; ca3 = r; }
    }
    float v0 = cmn0, v1 = cmn1, v2 = cmn2, v3 = cmn3;  // column duals
    u_s[c0i] = 0.0f; u_s[c1i] = 0.0f; u_s[c2i] = 0.0f; u_s[c3i] = 0.0f;
    rowcand_s[c0i] = 0x7fffffff; rowcand_s[c1i] = 0x7fffffff;
    rowcand_s[c2i] = 0x7fffffff; rowcand_s[c3i] = 0x7fffffff;
    __syncthreads();
    // greedy: each candidate row goes to the lowest claiming column
    atomicMin(&rowcand_s[ca0], c0i);
    atomicMin(&rowcand_s[ca1], c1i);
    atomicMin(&rowcand_s[ca2], c2i);
    atomicMin(&rowcand_s[ca3], c3i);
    __syncthreads();
    // mirrors: r4c = row matched to my 4 cols; c4r = col matched to my 4 rows
    int r4c0 = (rowcand_s[ca0] == c0i) ? ca0 : -1;
    int r4c1 = (rowcand_s[ca1] == c1i) ? ca1 : -1;
    int r4c2 = (rowcand_s[ca2] == c2i) ? ca2 : -1;
    int r4c3 = (rowcand_s[ca3] == c3i) ? ca3 : -1;
    const int rw0 = rowcand_s[c0i], rw1 = rowcand_s[c1i];
    const int rw2 = rowcand_s[c2i], rw3 = rowcand_s[c3i];
    int c4r0 = (rw0 == 0x7fffffff) ? -1 : rw0;
    int c4r1 = (rw1 == 0x7fffffff) ? -1 : rw1;
    int c4r2 = (rw2 == 0x7fffffff) ? -1 : rw2;
    int c4r3 = (rw3 == 0x7fffffff) ? -1 : rw3;
    int p0 = 0, p1 = 0, p2 = 0, p3 = 0;  // path (predecessor row per col)

    // free-row masks: mask k bit T <-> row 4T+k
    unsigned long long fm0 = __ballot(c4r0 < 0);
    unsigned long long fm1 = __ballot(c4r1 < 0);
    unsigned long long fm2 = __ballot(c4r2 < 0);
    unsigned long long fm3 = __ballot(c4r3 < 0);

    // ---- shortest augmenting path per free row ----
    while (fm0 | fm1 | fm2 | fm3) {
        int i;
        if (fm0)      { const int tt = __builtin_ctzll(fm0); fm0 &= fm0 - 1; i = tt * 4 + 0; }
        else if (fm1) { const int tt = __builtin_ctzll(fm1); fm1 &= fm1 - 1; i = tt * 4 + 1; }
        else if (fm2) { const int tt = __builtin_ctzll(fm2); fm2 &= fm2 - 1; i = tt * 4 + 2; }
        else          { const int tt = __builtin_ctzll(fm3); fm3 &= fm3 - 1; i = tt * 4 + 3; }

        float spc0 = INFINITY, spc1 = INFINITY, spc2 = INFINITY, spc3 = INFINITY;
        int   scan = 0;
        int   cur = i;
        float minVal = 0.0f;
        int   sink = -1;

        for (int step = 0; step < N_DIM; ++step) {
            const H4   h = ch[cur * BS + t];          // ds_read_b64
            const float ucur = u_s[cur];              // uniform LDS read (overlaps)
            const float add = minVal - ucur;

            unsigned key = 0xFFFFFFFFu;
            if (!(scan & 1)) {
                const float r = add + __low2float(h.a) - v0;
                if (r < spc0) { spc0 = r; p0 = cur; }
                const unsigned k = (fmap(spc0) & 0xFFFFFF00u) | (unsigned)c0i;
                if (k < key) key = k;
            }
            if (!(scan & 2)) {
                const float r = add + __high2float(h.a) - v1;
                if (r < spc1) { spc1 = r; p1 = cur; }
                const unsigned k = (fmap(spc1) & 0xFFFFFF00u) | (unsigned)c1i;
                if (k < key) key = k;
            }
            if (!(scan & 4)) {
                const float r = add + __low2float(h.b) - v2;
                if (r < spc2) { spc2 = r; p2 = cur; }
                const unsigned k = (fmap(spc2) & 0xFFFFFF00u) | (unsigned)c2i;
                if (k < key) key = k;
            }
            if (!(scan & 8)) {
                const float r = add + __high2float(h.b) - v3;
                if (r < spc3) { spc3 = r; p3 = cur; }
                const unsigned k = (fmap(spc3) & 0xFFFFFF00u) | (unsigned)c3i;
                if (k < key) key = k;
            }

            const unsigned gk = wave_min_u32(key);
            const int bi = (int)(gk & 0xFFu);
            // exact min value + matched row, two independent mirror lookups
            const float mv = rd4_f(spc0, spc1, spc2, spc3, bi);
            const int   r4 = rd4_i(r4c0, r4c1, r4c2, r4c3, bi);
            minVal = mv;
            if ((bi >> 2) == t) scan |= 1 << (bi & 3);
            if (r4 < 0) { sink = bi; break; }
            cur = r4;
        }

        // dual update (pre-augment mirrors; matched rows of scanned cols distinct)
        if (scan & 1) { const float dv = minVal - spc0; v0 -= dv; if (r4c0 >= 0) u_s[r4c0] += dv; }
        if (scan & 2) { const float dv = minVal - spc1; v1 -= dv; if (r4c1 >= 0) u_s[r4c1] += dv; }
        if (scan & 4) { const float dv = minVal - spc2; v2 -= dv; if (r4c2 >= 0) u_s[r4c2] += dv; }
        if (scan & 8) { const float dv = minVal - spc3; v3 -= dv; if (r4c3 >= 0) u_s[r4c3] += dv; }
        if (t == 0) u_s[i] += minVal;

        // augment alternating path (uniform walk over register mirrors)
        if (sink >= 0) {
            int jj = sink;
            while (true) {
                const int ii = rd4_i(p0, p1, p2, p3, jj);
                SET4(r4c0, r4c1, r4c2, r4c3, jj, ii);
                const int tmp = rd4_i(c4r0, c4r1, c4r2, c4r3, ii);
                SET4(c4r0, c4r1, c4r2, c4r3, ii, jj);
                jj = tmp;
                if (ii == i) break;
            }
        }
    }

    // ---- gather matched ORIGINAL f32 costs (4 rows per lane), reduce in f64 ----
    double s = 0.0;
    s += (double)cost[(size_t)(t * 4 + 0) * N_DIM + c4r0];
    s += (double)cost[(size_t)(t * 4 + 1) * N_DIM + c4r1];
    s += (double)cost[(size_t)(t * 4 + 2) * N_DIM + c4r2];
    s += (double)cost[(size_t)(t * 4 + 3) * N_DIM + c4r3];
    #pragma unroll
    for (int off = 32; off > 0; off >>= 1) s += __shfl_down(s, off);
    if (t == 0) batch_sums[b] = s;
}

__global__ void finalize_kernel(const double* __restrict__ batch_sums,
                                float* __restrict__ out) {
    const int t = threadIdx.x;  // 64 threads, one wave
    double s = batch_sums[t];
    #pragma unroll
    for (int off = 32; off > 0; off >>= 1) s += __shfl_down(s, off);
    if (t == 0) out[0] = (float)(s / (double)((long long)BATCH * N_DIM));
}

extern "C" void kernel_launch(void* const* d_in, const int* in_sizes, int n_in,
                              void* d_out, int out_size, void* d_ws, size_t ws_size,
                              hipStream_t stream) {
    const float* Dm = (const float*)d_in[0];
    float* out = (float*)d_out;
    double* sums = (double*)d_ws;  // 64 * 8 = 512 bytes

    lap_kernel<<<BATCH, BS, 0, stream>>>(Dm, sums);
    finalize_kernel<<<1, 64, 0, stream>>>(sums, out);
}

// Round 6
// 906.751 us; speedup vs baseline: 1.7009x; 1.4024x over previous
//
#include <hip/hip_runtime.h>
#include <hip/hip_fp16.h>

#define N_DIM 256
#define BATCH 64
#define BS 64   // one wave per block; lane t owns columns/rows 4t..4t+3

struct __align__(8) H4 { __half2 a, b; };

// monotone f32 -> u32 map (unsigned compare == float ascending)
__device__ __forceinline__ unsigned fmap(float f) {
    unsigned b = __float_as_uint(f);
    return (b & 0x80000000u) ? ~b : (b | 0x80000000u);
}

#define DPP_MINU(x, ctrl) do {                                                 \
    unsigned _s = (unsigned)__builtin_amdgcn_update_dpp((int)(x), (int)(x),    \
                                                        (ctrl), 0xf, 0xf, false); \
    (x) = ((x) < _s) ? (x) : _s;                                               \
} while (0)

// full-wave u32 min via DPP (row_shr 1/2/4/8, row_bcast15/31), bcast from lane 63
__device__ __forceinline__ unsigned wave_min_u32(unsigned x) {
    DPP_MINU(x, 0x111); DPP_MINU(x, 0x112); DPP_MINU(x, 0x114); DPP_MINU(x, 0x118);
    DPP_MINU(x, 0x142); DPP_MINU(x, 0x143);
    return (unsigned)__builtin_amdgcn_readlane((int)x, 63);
}

// uniform-index lookup from 4 per-lane mirror regs: 2 selects + 1 readlane
__device__ __forceinline__ int rd4_i(int x0, int x1, int x2, int x3, int idx) {
    const int sel = idx & 3, src = idx >> 2;
    int ab = (sel & 1) ? x1 : x0;
    int cd = (sel & 1) ? x3 : x2;
    int vv = (sel & 2) ? cd : ab;
    return __builtin_amdgcn_readlane(vv, src);
}
__device__ __forceinline__ float rd4_f(float x0, float x1, float x2, float x3, int idx) {
    return __int_as_float(rd4_i(__float_as_int(x0), __float_as_int(x1),
                                __float_as_int(x2), __float_as_int(x3), idx));
}

// owner-lane mirror update (idx wave-uniform)
#define SET4(x0, x1, x2, x3, idx, val) do {                                    \
    const int _sel = (idx) & 3;                                                \
    if (t == ((idx) >> 2)) {                                                   \
        if (_sel == 0) x0 = (val); else if (_sel == 1) x1 = (val);             \
        else if (_sel == 2) x2 = (val); else x3 = (val);                       \
    }                                                                          \
} while (0)

// One block = one wave = one batch element.
// JV LAP on the fp16-rounded cost matrix (staged in LDS):
//   1) column reduction + greedy init
//   2) lane-parallel augmenting row reduction (auction-style bids, <=12 passes)
//   3) shortest augmenting path (Dijkstra) for leftovers, register mirrors,
//      cached u32 argmin keys, no barriers in the inner loop.
// Duals stay feasible & matched-tight at every phase boundary, so the result
// is an exact optimum of the rounded matrix. Final gather uses ORIGINAL f32.
__global__ __launch_bounds__(BS) void lap_kernel(const float* __restrict__ Dm,
                                                 double* __restrict__ batch_sums) {
    const int b = blockIdx.x;
    const int t = threadIdx.x;  // 0..63
    const float* __restrict__ cost = Dm + (size_t)b * N_DIM * N_DIM;
    const float4* __restrict__ cost4 = (const float4*)cost;

    __shared__ H4       ch[N_DIM * BS];     // [row][lane]: 4 fp16 costs, 128 KB
    __shared__ float    u_s[N_DIM];
    __shared__ float    v_s[N_DIM];
    __shared__ int      row4col_s[N_DIM];
    __shared__ int      col4row_s[N_DIM];
    __shared__ int      queue_s[N_DIM];     // doubles as rowcand during greedy
    __shared__ unsigned bid_s[N_DIM];
    __shared__ int      qcnt_s;

    const int c0i = 4 * t, c1i = 4 * t + 1, c2i = 4 * t + 2, c3i = 4 * t + 3;

    // ---- stage fp16 matrix + column reduction on ROUNDED values ----
    float cmn0 = INFINITY, cmn1 = INFINITY, cmn2 = INFINITY, cmn3 = INFINITY;
    int   ca0 = 0, ca1 = 0, ca2 = 0, ca3 = 0;
    for (int r = 0; r < N_DIM; ++r) {
        const float4 c4 = cost4[r * BS + t];
        H4 h;
        h.a = __floats2half2_rn(c4.x, c4.y);
        h.b = __floats2half2_rn(c4.z, c4.w);
        ch[r * BS + t] = h;
        const float r0 = __low2float(h.a), r1 = __high2float(h.a);
        const float r2 = __low2float(h.b), r3 = __high2float(h.b);
        if (r0 < cmn0) { cmn0 = r0; ca0 = r; }
        if (r1 < cmn1) { cmn1 = r1; ca1 = r; }
        if (r2 < cmn2) { cmn2 = r2; ca2 = r; }
        if (r3 < cmn3) { cmn3 = r3; ca3 = r; }
    }
    {
        float4 vv; vv.x = cmn0; vv.y = cmn1; vv.z = cmn2; vv.w = cmn3;
        ((float4*)v_s)[t] = vv;
        float4 zz; zz.x = 0.f; zz.y = 0.f; zz.z = 0.f; zz.w = 0.f;
        ((float4*)u_s)[t] = zz;
        int4 mm; mm.x = -1; mm.y = -1; mm.z = -1; mm.w = -1;
        ((int4*)row4col_s)[t] = mm;
        ((int4*)col4row_s)[t] = mm;
        int4 rc; rc.x = 0x7fffffff; rc.y = 0x7fffffff; rc.z = 0x7fffffff; rc.w = 0x7fffffff;
        ((int4*)queue_s)[t] = rc;   // rowcand
        uint4 bb; bb.x = ~0u; bb.y = ~0u; bb.z = ~0u; bb.w = ~0u;
        ((uint4*)bid_s)[t] = bb;
    }
    __syncthreads();
    // greedy: each candidate row goes to the lowest claiming column
    atomicMin(&queue_s[ca0], c0i);
    atomicMin(&queue_s[ca1], c1i);
    atomicMin(&queue_s[ca2], c2i);
    atomicMin(&queue_s[ca3], c3i);
    __syncthreads();
    if (queue_s[ca0] == c0i) { row4col_s[c0i] = ca0; col4row_s[ca0] = c0i; }
    if (queue_s[ca1] == c1i) { row4col_s[c1i] = ca1; col4row_s[ca1] = c1i; }
    if (queue_s[ca2] == c2i) { row4col_s[c2i] = ca2; col4row_s[ca2] = c2i; }
    if (queue_s[ca3] == c3i) { row4col_s[c3i] = ca3; col4row_s[ca3] = c3i; }
    __syncthreads();

    // ---- lane-parallel augmenting row reduction (auction-style) ----
    for (int pass = 0; pass < 12; ++pass) {
        if (t == 0) qcnt_s = 0;
        __syncthreads();
        {
            const int4 my = ((const int4*)col4row_s)[t];
            const int nf = (my.x < 0) + (my.y < 0) + (my.z < 0) + (my.w < 0);
            if (nf) {
                int pos = atomicAdd(&qcnt_s, nf);
                if (my.x < 0) queue_s[pos++] = c0i;
                if (my.y < 0) queue_s[pos++] = c1i;
                if (my.z < 0) queue_s[pos++] = c2i;
                if (my.w < 0) queue_s[pos++] = c3i;
            }
        }
        __syncthreads();
        const int n = qcnt_s;
        if (n == 0) break;
        const int my_row = (t < n) ? queue_s[t] : -1;
        float d1 = INFINITY, d2 = INFINITY;
        int   j1 = 0;
        if (my_row >= 0) {
            const int base = my_row * BS;
            for (int l = 0; l < BS; ++l) {
                const int l2 = (l + t) & 63;  // rotate start: avoid bank pileup
                const H4 h = ch[base + l2];
                const float4 vv = ((const float4*)v_s)[l2];
                float d;
                d = __low2float(h.a)  - vv.x; if (d < d1) { d2 = d1; d1 = d; j1 = 4 * l2 + 0; } else if (d < d2) d2 = d;
                d = __high2float(h.a) - vv.y; if (d < d1) { d2 = d1; d1 = d; j1 = 4 * l2 + 1; } else if (d < d2) d2 = d;
                d = __low2float(h.b)  - vv.z; if (d < d1) { d2 = d1; d1 = d; j1 = 4 * l2 + 2; } else if (d < d2) d2 = d;
                d = __high2float(h.b) - vv.w; if (d < d1) { d2 = d1; d1 = d; j1 = 4 * l2 + 3; } else if (d < d2) d2 = d;
            }
            atomicMin(&bid_s[j1], (fmap(d1) & 0xFFFFFF00u) | (unsigned)t);
        }
        __syncthreads();
        if (my_row >= 0) {
            const unsigned mybid = (fmap(d1) & 0xFFFFFF00u) | (unsigned)t;
            if (bid_s[j1] == mybid) {  // unique winner per column
                const int i0 = row4col_s[j1];
                row4col_s[j1] = my_row;
                col4row_s[my_row] = j1;
                if (i0 >= 0) col4row_s[i0] = -1;
                u_s[my_row] = d2;
                v_s[j1] += d1 - d2;    // v only decreases -> duals stay feasible
                bid_s[j1] = ~0u;       // reset for next pass
            }
        }
        __syncthreads();
    }

    // ---- refresh register state from LDS ----
    const float4 vv4 = ((const float4*)v_s)[t];
    float v0 = vv4.x, v1 = vv4.y, v2 = vv4.z, v3 = vv4.w;
    const int4 m4 = ((const int4*)row4col_s)[t];
    int r4c0 = m4.x, r4c1 = m4.y, r4c2 = m4.z, r4c3 = m4.w;
    const int4 y4 = ((const int4*)col4row_s)[t];
    int c4r0 = y4.x, c4r1 = y4.y, c4r2 = y4.z, c4r3 = y4.w;
    int p0 = 0, p1 = 0, p2 = 0, p3 = 0;

    unsigned long long fm0 = __ballot(c4r0 < 0);
    unsigned long long fm1 = __ballot(c4r1 < 0);
    unsigned long long fm2 = __ballot(c4r2 < 0);
    unsigned long long fm3 = __ballot(c4r3 < 0);

    const unsigned KINF0 = (fmap(INFINITY) & 0xFFFFFF00u) | (unsigned)c0i;
    const unsigned KINF1 = (fmap(INFINITY) & 0xFFFFFF00u) | (unsigned)c1i;
    const unsigned KINF2 = (fmap(INFINITY) & 0xFFFFFF00u) | (unsigned)c2i;
    const unsigned KINF3 = (fmap(INFINITY) & 0xFFFFFF00u) | (unsigned)c3i;

    // ---- shortest augmenting path per remaining free row ----
    while (fm0 | fm1 | fm2 | fm3) {
        int i;
        if (fm0)      { const int tt = __builtin_ctzll(fm0); fm0 &= fm0 - 1; i = tt * 4 + 0; }
        else if (fm1) { const int tt = __builtin_ctzll(fm1); fm1 &= fm1 - 1; i = tt * 4 + 1; }
        else if (fm2) { const int tt = __builtin_ctzll(fm2); fm2 &= fm2 - 1; i = tt * 4 + 2; }
        else          { const int tt = __builtin_ctzll(fm3); fm3 &= fm3 - 1; i = tt * 4 + 3; }

        float spc0 = INFINITY, spc1 = INFINITY, spc2 = INFINITY, spc3 = INFINITY;
        unsigned key0 = KINF0, key1 = KINF1, key2 = KINF2, key3 = KINF3;
        int   scan = 0;
        int   cur = i;
        float minVal = 0.0f;
        int   sink = -1;

        while (true) {
            const H4    h = ch[cur * BS + t];     // ds_read_b64
            const float ucur = u_s[cur];          // uniform LDS read (parallel)
            const float add = minVal - ucur;

            // unconditional relax: scanned cols can't improve (r >= minVal >= spc)
            float r;
            r = add + __low2float(h.a)  - v0;
            if (r < spc0) { spc0 = r; p0 = cur; key0 = (fmap(r) & 0xFFFFFF00u) | (unsigned)c0i; }
            r = add + __high2float(h.a) - v1;
            if (r < spc1) { spc1 = r; p1 = cur; key1 = (fmap(r) & 0xFFFFFF00u) | (unsigned)c1i; }
            r = add + __low2float(h.b)  - v2;
            if (r < spc2) { spc2 = r; p2 = cur; key2 = (fmap(r) & 0xFFFFFF00u) | (unsigned)c2i; }
            r = add + __high2float(h.b) - v3;
            if (r < spc3) { spc3 = r; p3 = cur; key3 = (fmap(r) & 0xFFFFFF00u) | (unsigned)c3i; }

            unsigned k01 = (key0 < key1) ? key0 : key1;
            unsigned k23 = (key2 < key3) ? key2 : key3;
            const unsigned gk = wave_min_u32((k01 < k23) ? k01 : k23);
            const int bi = (int)(gk & 0xFFu);

            const float mv = rd4_f(spc0, spc1, spc2, spc3, bi);   // exact min
            const int   r4 = rd4_i(r4c0, r4c1, r4c2, r4c3, bi);   // matched row
            minVal = mv;
            if (t == (bi >> 2)) {
                const int s = bi & 3;
                scan |= 1 << s;
                if (s == 0) key0 = ~0u; else if (s == 1) key1 = ~0u;
                else if (s == 2) key2 = ~0u; else key3 = ~0u;
            }
            if (r4 < 0) { sink = bi; break; }
            cur = r4;
        }

        // dual update (pre-augment mirrors; matched rows of scanned cols distinct)
        if (scan & 1) { const float dv = minVal - spc0; v0 -= dv; if (r4c0 >= 0) u_s[r4c0] += dv; }
        if (scan & 2) { const float dv = minVal - spc1; v1 -= dv; if (r4c1 >= 0) u_s[r4c1] += dv; }
        if (scan & 4) { const float dv = minVal - spc2; v2 -= dv; if (r4c2 >= 0) u_s[r4c2] += dv; }
        if (scan & 8) { const float dv = minVal - spc3; v3 -= dv; if (r4c3 >= 0) u_s[r4c3] += dv; }
        if (t == 0) u_s[i] += minVal;

        // augment alternating path (uniform walk over register mirrors)
        if (sink >= 0) {
            int jj = sink;
            while (true) {
                const int ii = rd4_i(p0, p1, p2, p3, jj);
                SET4(r4c0, r4c1, r4c2, r4c3, jj, ii);
                const int tmp = rd4_i(c4r0, c4r1, c4r2, c4r3, ii);
                SET4(c4r0, c4r1, c4r2, c4r3, ii, jj);
                jj = tmp;
                if (ii == i) break;
            }
        }
    }

    // ---- gather matched ORIGINAL f32 costs (4 rows per lane), reduce in f64 ----
    double s = 0.0;
    s += (double)cost[(size_t)(t * 4 + 0) * N_DIM + c4r0];
    s += (double)cost[(size_t)(t * 4 + 1) * N_DIM + c4r1];
    s += (double)cost[(size_t)(t * 4 + 2) * N_DIM + c4r2];
    s += (double)cost[(size_t)(t * 4 + 3) * N_DIM + c4r3];
    #pragma unroll
    for (int off = 32; off > 0; off >>= 1) s += __shfl_down(s, off);
    if (t == 0) batch_sums[b] = s;
}

__global__ void finalize_kernel(const double* __restrict__ batch_sums,
                                float* __restrict__ out) {
    const int t = threadIdx.x;  // 64 threads, one wave
    double s = batch_sums[t];
    #pragma unroll
    for (int off = 32; off > 0; off >>= 1) s += __shfl_down(s, off);
    if (t == 0) out[0] = (float)(s / (double)((long long)BATCH * N_DIM));
}

extern "C" void kernel_launch(void* const* d_in, const int* in_sizes, int n_in,
                              void* d_out, int out_size, void* d_ws, size_t ws_size,
                              hipStream_t stream) {
    const float* Dm = (const float*)d_in[0];
    float* out = (float*)d_out;
    double* sums = (double*)d_ws;  // 64 * 8 = 512 bytes

    lap_kernel<<<BATCH, BS, 0, stream>>>(Dm, sums);
    finalize_kernel<<<1, 64, 0, stream>>>(sums, out);
}